// Round 4
// baseline (542.401 us; speedup 1.0000x reference)
//
#include <hip/hip_runtime.h>
#include <hip/hip_bf16.h>

#define NF 128
#define NATOMS 100000
#define NGRAPH 128

#define MT 32
#define NTILES (NATOMS/MT)    // 3125
#define GRID 256
#define NTHR 256              // 4 waves

// stage: 64 chunks of 256 floats, padded to 264 floats each (bank rotation)
#define CHW 264
#define SBASE_V (16*CHW)      // v chunks start after 16 s chunks
#define STAGE_FLOATS (64*CHW) // 16896 floats = 67.6 KB

// blob layout per layer (bf16 elems): frags for 32x32x16 MFMA B-operand
#define OW1 0
#define OW2 16384
#define OA1 32768
#define OA2 65536
#define LAYER_SZ 98304

typedef __attribute__((ext_vector_type(8)))  short bf16x8;
typedef __attribute__((ext_vector_type(16))) float f32x16;

static __device__ __forceinline__ float bf2f(__hip_bfloat16 x) { return __bfloat162float(x); }
static __device__ __forceinline__ __hip_bfloat16 f2bf(float x) { return __float2bfloat16(x); }
static __device__ __forceinline__ unsigned short f2bfu(float x) {
  __hip_bfloat16 h = __float2bfloat16(x);
  return *(unsigned short*)&h;
}
static __device__ __forceinline__ bf16x8 pack8(float4 lo, float4 hi) {
  union { unsigned short s[8]; bf16x8 v; } u;
  u.s[0]=f2bfu(lo.x); u.s[1]=f2bfu(lo.y); u.s[2]=f2bfu(lo.z); u.s[3]=f2bfu(lo.w);
  u.s[4]=f2bfu(hi.x); u.s[5]=f2bfu(hi.y); u.s[6]=f2bfu(hi.z); u.s[7]=f2bfu(hi.w);
  return u.v;
}

#define GLB(p) ((const __attribute__((address_space(1))) void*)(p))
#define LDS(p) ((__attribute__((address_space(3))) void*)(p))

// Barrier that waits LDS ops only — leaves global_load_lds (vmcnt) in flight.
#define BAR_LGKM() asm volatile("s_waitcnt lgkmcnt(0)\n\ts_barrier" ::: "memory")

// A-frag read with XOR swizzle; gr = granules(16B) per row
static __device__ __forceinline__ bf16x8 ldfrag(const __hip_bfloat16* buf, int gr, int row, int gi) {
  return *(const bf16x8*)&buf[(row*gr + (gi ^ (row & 7)))*8];
}
// scalar bf16 store with XOR swizzle
static __device__ __forceinline__ void stb(__hip_bfloat16* buf, int gr, int row, int colq, float v) {
  int gi = colq >> 3, off = colq & 7;
  buf[(row*gr + (gi ^ (row & 7)))*8 + off] = f2bf(v);
}

// Pre-swizzle weights into per-MFMA B-fragment order for 32x32x16:
// frag(lane)[j] = W[ks*16 + (lane>>5)*8 + j][ct*32 + (lane&31)]
__global__ __launch_bounds__(256)
void prep_weights(const float* __restrict__ w1, const float* __restrict__ w2,
                  const float* __restrict__ a1w, const float* __restrict__ a2w,
                  __hip_bfloat16* __restrict__ blob) {
  int gid = blockIdx.x * 256 + threadIdx.x;
  int lane = gid & 63;
  int g2 = gid >> 6;                             // 0..383
  int layer = g2 / 192;
  int r = g2 - layer * 192;
  const float* W; int N, ct, ks; size_t off;
  if (r < 32)       { W = w1  + layer*16384; N = 128; ct = r >> 3;        ks = r & 7;        off = OW1 + (size_t)r*512; }
  else if (r < 64)  { int q = r-32;  W = w2  + layer*16384; N = 128; ct = q >> 3;  ks = q & 7;  off = OW2 + (size_t)q*512; }
  else if (r < 128) { int q = r-64;  W = a1w + layer*32768; N = 128; ct = q >> 4;  ks = q & 15; off = OA1 + (size_t)q*512; }
  else              { int q = r-128; W = a2w + layer*32768; N = 256; ct = q >> 3;  ks = q & 7;  off = OA2 + (size_t)q*512; }
  int k0 = ks*16 + ((lane >> 5) << 3);
  int n  = ct*32 + (lane & 31);
  __hip_bfloat16* o = blob + (size_t)layer*LAYER_SZ + off + (size_t)lane*8;
  #pragma unroll
  for (int j = 0; j < 8; ++j) o[j] = f2bf(W[(size_t)(k0 + j)*N + n]);
}

// Persistent fused kernel: 256 blocks x 256 thr (4 waves, 1/SIMD).
// Weights register-resident; inter-phase barriers are lgkm-only so the
// global_load_lds prefetch of tile t+GRID overlaps the whole tile-t compute.
__global__ __launch_bounds__(NTHR, 1)
void fused_equiv(const float* __restrict__ s_g, const float* __restrict__ v_g,
                 const __hip_bfloat16* __restrict__ blob,
                 const float* __restrict__ a1b, const float* __restrict__ a2b,
                 const float* __restrict__ out_w, const float* __restrict__ out_b,
                 float* __restrict__ sc) {
  __shared__ float stage[STAGE_FLOATS];             // 67.6 KB raw fp32 (padded chunks)
  __shared__ __hip_bfloat16 vcur[3*MT*NF];          // 24 KB, XOR-swizzled planes
  __shared__ __hip_bfloat16 hbuf[MT*2*NF];          // 16 KB, [s | n2]
  __shared__ __hip_bfloat16 h1[MT*NF];              // 8 KB

  const int tid  = threadIdx.x;
  const int wave = tid >> 6;
  const int lane = tid & 63;
  const int row  = lane & 31;
  const int half = lane >> 5;
  const int col  = wave*32 + row;

  // ---- weight fragments -> registers (once) ----
  const __hip_bfloat16* L1 = blob;
  const __hip_bfloat16* L2w = blob + LAYER_SZ;
  bf16x8 w1f[8], w2f[8], a1f[16], asf[8], agf[8];
  bf16x8 w2g[8], a1g[16], asg[8];
  #pragma unroll
  for (int ks = 0; ks < 8; ++ks) {
    w1f[ks] = *(const bf16x8*)&L1[OW1 + ((size_t)(wave*8 + ks)*64 + lane)*8];
    w2f[ks] = *(const bf16x8*)&L1[OW2 + ((size_t)(wave*8 + ks)*64 + lane)*8];
    asf[ks] = *(const bf16x8*)&L1[OA2 + ((size_t)(wave*8 + ks)*64 + lane)*8];
    agf[ks] = *(const bf16x8*)&L1[OA2 + ((size_t)((wave+4)*8 + ks)*64 + lane)*8];
    w2g[ks] = *(const bf16x8*)&L2w[OW2 + ((size_t)(wave*8 + ks)*64 + lane)*8];
    asg[ks] = *(const bf16x8*)&L2w[OA2 + ((size_t)(wave*8 + ks)*64 + lane)*8];
  }
  #pragma unroll
  for (int ks = 0; ks < 16; ++ks) {
    a1f[ks] = *(const bf16x8*)&L1[OA1 + ((size_t)(wave*16 + ks)*64 + lane)*8];
    a1g[ks] = *(const bf16x8*)&L2w[OA1 + ((size_t)(wave*16 + ks)*64 + lane)*8];
  }
  const float b1a = a1b[col];
  const float b1g = a1b[NF + col];
  const float b2s = a2b[col];
  const float b2g = a2b[NF + col];
  const float b2s2 = a2b[2*NF + col];
  const float outb = out_b[0];
  const int ha = tid >> 3, hk = tid & 7;
  float owf[16];
  #pragma unroll
  for (int j = 0; j < 16; ++j) owf[j] = out_w[hk*16 + j];

  // ---- staging: 64 chunks of 1 KB (padded dst), 16 per wave ----
  auto stage_issue = [&](int tile) {
    size_t a0 = (size_t)tile * MT;
    #pragma unroll
    for (int i = 0; i < 16; ++i) {
      int g = wave*16 + i;
      const float* src = (g < 16) ? (s_g + a0*NF + g*256 + lane*4)
                                  : (v_g + a0*3*NF + (g-16)*256 + lane*4);
      float* dst = stage + g*CHW + lane*4;
      __builtin_amdgcn_global_load_lds(GLB(src), LDS(dst), 16, 0, 0);
    }
  };

  int t = blockIdx.x;
  if (t < NTILES) stage_issue(t);
  __syncthreads();

  for (; t < NTILES; t += GRID) {
    const int a0 = t * MT;

    // ---- convert: stage fp32 -> bf16 swizzled (conflict-free mapping) ----
    {
      int ar = tid >> 3;               // atom row 0..31
      int t8 = tid & 7;
      #pragma unroll
      for (int su = 0; su < 2; ++su) {
        int gi = t8 + 8*su;            // granule 0..15
        const float* sp = &stage[(ar>>1)*CHW + (ar&1)*128 + gi*8];
        float4 lo = *(const float4*)sp;
        float4 hi = *(const float4*)(sp + 4);
        *(bf16x8*)&hbuf[(ar*32 + (gi ^ (ar & 7)))*8] = pack8(lo, hi);
      }
      #pragma unroll
      for (int c = 0; c < 3; ++c)
        #pragma unroll
        for (int su = 0; su < 2; ++su) {
          int gi = t8 + 8*su;
          int R = ar*3 + c;            // v row 0..95
          const float* sp = &stage[SBASE_V + (R>>1)*CHW + (R&1)*128 + gi*8];
          float4 lo = *(const float4*)sp;
          float4 hi = *(const float4*)(sp + 4);
          *(bf16x8*)&vcur[c*(MT*NF) + (ar*16 + (gi ^ (ar & 7)))*8] = pack8(lo, hi);
        }
    }
    BAR_LGKM();

    // prefetch next tile (stays in flight across all lgkm-only barriers below)
    if (t + GRID < NTILES) stage_issue(t + GRID);

    f32x16 v1a[3];

    // ---- L1 Phase A: v @ [w1|w2]; n2 in registers ----
    {
      float n2sq[16];
      #pragma unroll
      for (int i = 0; i < 16; ++i) n2sq[i] = 0.f;
      #pragma unroll
      for (int c = 0; c < 3; ++c) {
        const __hip_bfloat16* vb = vcur + c*(MT*NF);
        f32x16 acc1, acc2;
        #pragma unroll
        for (int i = 0; i < 16; ++i) { acc1[i] = 0.f; acc2[i] = 0.f; }
        #pragma unroll
        for (int ks = 0; ks < 8; ++ks) {
          bf16x8 af = ldfrag(vb, 16, row, ks*2 + half);
          acc1 = __builtin_amdgcn_mfma_f32_32x32x16_bf16(af, w1f[ks], acc1, 0, 0, 0);
          acc2 = __builtin_amdgcn_mfma_f32_32x32x16_bf16(af, w2f[ks], acc2, 0, 0, 0);
        }
        v1a[c] = acc1;
        #pragma unroll
        for (int i = 0; i < 16; ++i) n2sq[i] += acc2[i]*acc2[i];
      }
      #pragma unroll
      for (int i = 0; i < 16; ++i) {
        int r = (i & 3) + 8*(i >> 2) + 4*half;
        stb(hbuf, 32, r, NF + col, sqrtf(n2sq[i]));
      }
    }
    BAR_LGKM();

    // ---- L1 Phase B: [s|n2] @ a1w + bias, silu -> h1 ----
    {
      f32x16 h;
      #pragma unroll
      for (int i = 0; i < 16; ++i) h[i] = 0.f;
      #pragma unroll
      for (int ks = 0; ks < 16; ++ks) {
        bf16x8 af = ldfrag(hbuf, 32, row, ks*2 + half);
        h = __builtin_amdgcn_mfma_f32_32x32x16_bf16(af, a1f[ks], h, 0, 0, 0);
      }
      #pragma unroll
      for (int i = 0; i < 16; ++i) {
        int r = (i & 3) + 8*(i >> 2) + 4*half;
        float x = h[i] + b1a;
        stb(h1, 16, r, col, x / (1.0f + __expf(-x)));
      }
    }
    BAR_LGKM();

    // ---- L1 Phase C: h1 @ a2w -> s1 (hbuf) + gate*v1 -> vcur ----
    {
      f32x16 hs, hg;
      #pragma unroll
      for (int i = 0; i < 16; ++i) { hs[i] = 0.f; hg[i] = 0.f; }
      #pragma unroll
      for (int ks = 0; ks < 8; ++ks) {
        bf16x8 af = ldfrag(h1, 16, row, ks*2 + half);
        hs = __builtin_amdgcn_mfma_f32_32x32x16_bf16(af, asf[ks], hs, 0, 0, 0);
        hg = __builtin_amdgcn_mfma_f32_32x32x16_bf16(af, agf[ks], hg, 0, 0, 0);
      }
      #pragma unroll
      for (int i = 0; i < 16; ++i) {
        int r = (i & 3) + 8*(i >> 2) + 4*half;
        stb(hbuf, 32, r, col, hs[i] + b2s);
        float g = hg[i] + b2g;
        stb(vcur,           16, r, col, g * v1a[0][i]);
        stb(vcur +   MT*NF, 16, r, col, g * v1a[1][i]);
        stb(vcur + 2*MT*NF, 16, r, col, g * v1a[2][i]);
      }
    }
    BAR_LGKM();

    // ---- L2 Phase A: v' @ w2 -> n2 (v1/gate of last layer unused) ----
    {
      float n2sq[16];
      #pragma unroll
      for (int i = 0; i < 16; ++i) n2sq[i] = 0.f;
      #pragma unroll
      for (int c = 0; c < 3; ++c) {
        const __hip_bfloat16* vb = vcur + c*(MT*NF);
        f32x16 acc2;
        #pragma unroll
        for (int i = 0; i < 16; ++i) acc2[i] = 0.f;
        #pragma unroll
        for (int ks = 0; ks < 8; ++ks) {
          bf16x8 af = ldfrag(vb, 16, row, ks*2 + half);
          acc2 = __builtin_amdgcn_mfma_f32_32x32x16_bf16(af, w2g[ks], acc2, 0, 0, 0);
        }
        #pragma unroll
        for (int i = 0; i < 16; ++i) n2sq[i] += acc2[i]*acc2[i];
      }
      #pragma unroll
      for (int i = 0; i < 16; ++i) {
        int r = (i & 3) + 8*(i >> 2) + 4*half;
        stb(hbuf, 32, r, NF + col, sqrtf(n2sq[i]));
      }
    }
    BAR_LGKM();

    // ---- L2 Phase B ----
    {
      f32x16 h;
      #pragma unroll
      for (int i = 0; i < 16; ++i) h[i] = 0.f;
      #pragma unroll
      for (int ks = 0; ks < 16; ++ks) {
        bf16x8 af = ldfrag(hbuf, 32, row, ks*2 + half);
        h = __builtin_amdgcn_mfma_f32_32x32x16_bf16(af, a1g[ks], h, 0, 0, 0);
      }
      #pragma unroll
      for (int i = 0; i < 16; ++i) {
        int r = (i & 3) + 8*(i >> 2) + 4*half;
        float x = h[i] + b1g;
        stb(h1, 16, r, col, x / (1.0f + __expf(-x)));
      }
    }
    BAR_LGKM();

    // ---- L2 Phase C: s2 -> hbuf s-half ----
    {
      f32x16 hs;
      #pragma unroll
      for (int i = 0; i < 16; ++i) hs[i] = 0.f;
      #pragma unroll
      for (int ks = 0; ks < 8; ++ks) {
        bf16x8 af = ldfrag(h1, 16, row, ks*2 + half);
        hs = __builtin_amdgcn_mfma_f32_32x32x16_bf16(af, asg[ks], hs, 0, 0, 0);
      }
      #pragma unroll
      for (int i = 0; i < 16; ++i) {
        int r = (i & 3) + 8*(i >> 2) + 4*half;
        stb(hbuf, 32, r, col, hs[i] + b2s2);
      }
    }
    BAR_LGKM();

    // ---- head: sc[atom] = dot(s2, out_w) + out_b ----
    {
      float p = 0.f;
      #pragma unroll
      for (int j = 0; j < 16; ++j) {
        int f = hk*16 + j;
        p += bf2f(hbuf[(ha*32 + ((f >> 3) ^ (ha & 7)))*8 + (f & 7)]) * owf[j];
      }
      p += __shfl_down(p, 4, 8);
      p += __shfl_down(p, 2, 8);
      p += __shfl_down(p, 1, 8);
      if (hk == 0) sc[a0 + ha] = p + outb;
    }
    __syncthreads();   // full drain: stage prefetch must be resident; hbuf reuse
  }
}

// Stage 1: partial[b*16+chunk] over 6250-atom chunks (2048 blocks)
__global__ __launch_bounds__(256)
void reduce_partial(const float* __restrict__ mask, const float* __restrict__ sc,
                    float* __restrict__ partial) {
  int b  = blockIdx.x >> 4;
  int ch = blockIdx.x & 15;
  int n0 = ch * (NATOMS/16);
  int n1 = n0 + (NATOMS/16);
  const float* mrow = mask + (size_t)b * NATOMS;
  float acc = 0.f;
  for (int n = n0 + threadIdx.x; n < n1; n += 256) acc += mrow[n] * sc[n];
  #pragma unroll
  for (int d = 32; d > 0; d >>= 1) acc += __shfl_down(acc, d, 64);
  __shared__ float red[4];
  if ((threadIdx.x & 63) == 0) red[threadIdx.x >> 6] = acc;
  __syncthreads();
  if (threadIdx.x == 0) partial[blockIdx.x] = red[0] + red[1] + red[2] + red[3];
}

__global__ void reduce_final(const float* __restrict__ partial, float* __restrict__ out) {
  int b = threadIdx.x;
  if (b < NGRAPH) {
    float s = 0.f;
    #pragma unroll
    for (int k = 0; k < 16; ++k) s += partial[b*16 + k];
    out[b] = s;
  }
}

extern "C" void kernel_launch(void* const* d_in, const int* in_sizes, int n_in,
                              void* d_out, int out_size, void* d_ws, size_t ws_size,
                              hipStream_t stream) {
  const float* s    = (const float*)d_in[0];
  const float* v    = (const float*)d_in[1];
  // d_in[2] = r, unused
  const float* mask = (const float*)d_in[3];
  const float* w1   = (const float*)d_in[4];
  const float* w2   = (const float*)d_in[5];
  const float* a1w  = (const float*)d_in[6];
  const float* a1b  = (const float*)d_in[7];
  const float* a2w  = (const float*)d_in[8];
  const float* a2b  = (const float*)d_in[9];
  const float* outw = (const float*)d_in[10];
  const float* outb = (const float*)d_in[11];

  char* ws = (char*)d_ws;
  __hip_bfloat16* blob = (__hip_bfloat16*)ws;                      // 384 KB
  float* sc      = (float*)(ws + (size_t)2*LAYER_SZ*2);            // 400 KB
  float* partial = (float*)(ws + (size_t)2*LAYER_SZ*2 + NATOMS*4); // 8 KB

  prep_weights<<<96, 256, 0, stream>>>(w1, w2, a1w, a2w, blob);
  fused_equiv<<<GRID, NTHR, 0, stream>>>(s, v, blob, a1b, a2b, outw, outb, sc);
  reduce_partial<<<NGRAPH*16, 256, 0, stream>>>(mask, sc, partial);
  reduce_final<<<1, 128, 0, stream>>>(partial, (float*)d_out);
}

// Round 5
// 439.542 us; speedup vs baseline: 1.2340x; 1.2340x over previous
//
#include <hip/hip_runtime.h>
#include <hip/hip_bf16.h>

#define NF 128
#define NF2 256
#define NATOMS 100000
#define NGRAPH 128

#define MT 32
#define NBLK (NATOMS/MT)      // 3125
#define NTHR 512              // 8 waves

// blob layout per layer (bf16 elems): frags for 16x16x32 MFMA B-operand
#define OW1 0                 // 8ct x 4ks
#define OW2 16384
#define OA1 32768             // 8ct x 8ks
#define OA2 65536             // 16ct x 4ks (ct0-7 = s-half, ct8-15 = gate)
#define LAYER_SZ 98304

typedef __attribute__((ext_vector_type(8))) short bf16x8;
typedef __attribute__((ext_vector_type(4))) float f32x4;

static __device__ __forceinline__ float bf2f(__hip_bfloat16 x) { return __bfloat162float(x); }
static __device__ __forceinline__ __hip_bfloat16 f2bf(float x) { return __float2bfloat16(x); }
static __device__ __forceinline__ unsigned short f2bfu(float x) {
  __hip_bfloat16 h = __float2bfloat16(x);
  return *(unsigned short*)&h;
}
static __device__ __forceinline__ bf16x8 pack8(float4 lo, float4 hi) {
  union { unsigned short s[8]; bf16x8 v; } u;
  u.s[0]=f2bfu(lo.x); u.s[1]=f2bfu(lo.y); u.s[2]=f2bfu(lo.z); u.s[3]=f2bfu(lo.w);
  u.s[4]=f2bfu(hi.x); u.s[5]=f2bfu(hi.y); u.s[6]=f2bfu(hi.z); u.s[7]=f2bfu(hi.w);
  return u.v;
}

// Swizzled LDS tile: 16B granules, granule index XORed with (row&7).
// gr = granules per row. Conflict-free for quarter-wave row/col patterns used here.
static __device__ __forceinline__ bf16x8 ldfrag(const __hip_bfloat16* buf, int gr, int row, int gi) {
  return *(const bf16x8*)&buf[(row*gr + (gi ^ (row & 7)))*8];
}
static __device__ __forceinline__ void stb(__hip_bfloat16* buf, int gr, int row, int col, float v) {
  int gi = col >> 3, off = col & 7;
  buf[(row*gr + (gi ^ (row & 7)))*8 + off] = f2bf(v);
}
static __device__ __forceinline__ float ldb(const __hip_bfloat16* buf, int gr, int row, int col) {
  int gi = col >> 3, off = col & 7;
  return bf2f(buf[(row*gr + (gi ^ (row & 7)))*8 + off]);
}

// Pre-swizzle weights into per-MFMA B-fragment order for 16x16x32:
// blob[((ct*nks + ks)*64 + lane)*8 + j] = W[ks*32 + (lane>>4)*8 + j][ct*16 + (lane&15)]
__global__ __launch_bounds__(256)
void prep_weights(const float* __restrict__ w1, const float* __restrict__ w2,
                  const float* __restrict__ a1w, const float* __restrict__ a2w,
                  __hip_bfloat16* __restrict__ blob) {
  int gid = blockIdx.x * 256 + threadIdx.x;           // 24576 total
  int layer = gid / 12288;
  int r = gid - layer * 12288;
  const float* W; int N, nks, g; __hip_bfloat16* dst;
  if (r < 2048)      { W = w1  + layer*NF*NF;  N = NF;  nks = 4; dst = blob + layer*LAYER_SZ + OW1; g = r; }
  else if (r < 4096) { W = w2  + layer*NF*NF;  N = NF;  nks = 4; dst = blob + layer*LAYER_SZ + OW2; g = r - 2048; }
  else if (r < 8192) { W = a1w + layer*NF2*NF; N = NF;  nks = 8; dst = blob + layer*LAYER_SZ + OA1; g = r - 4096; }
  else               { W = a2w + layer*NF*NF2; N = NF2; nks = 4; dst = blob + layer*LAYER_SZ + OA2; g = r - 8192; }
  int lane = g & 63;
  int ks = (g >> 6) % nks;
  int ct = g / (64 * nks);
  int k0 = ks * 32 + ((lane >> 4) << 3);
  int n  = ct * 16 + (lane & 15);
  __hip_bfloat16* o = dst + (size_t)((ct * nks + ks) * 64 + lane) * 8;
  #pragma unroll
  for (int j = 0; j < 8; ++j) o[j] = f2bf(W[(size_t)(k0 + j) * N + n]);
}

// High-occupancy fused kernel: 3125 blocks x 512 thr (8 waves), 48 KB LDS
// -> 3 blocks/CU, 24 waves/CU. Weight B-frags streamed from L2 each phase
// (transient); v1 parked in LDS; n2 and gate computed in the owning lane.
__global__ __launch_bounds__(NTHR, 6)
void fused_equiv(const float* __restrict__ s_g, const float* __restrict__ v_g,
                 const __hip_bfloat16* __restrict__ blob,
                 const float* __restrict__ a1b, const float* __restrict__ a2b,
                 const float* __restrict__ out_w, const float* __restrict__ out_b,
                 float* __restrict__ sc) {
  __shared__ __hip_bfloat16 vcur[3*MT*NF];   // 24 KB, 3 c-planes, swizzled, gr=16
  __shared__ __hip_bfloat16 hbuf[MT*NF2];    // 16 KB, [s | n2], gr=32
  __shared__ __hip_bfloat16 h1[MT*NF];       // 8 KB, gr=16

  const int tid  = threadIdx.x;
  const int wave = tid >> 6;                 // 0..7
  const int lane = tid & 63;
  const int l15  = lane & 15;
  const int quad = lane >> 4;
  const int a0   = blockIdx.x * MT;
  const int col  = wave*16 + l15;            // output column this lane owns

  // ---- stage: global fp32 -> bf16 swizzled LDS (coalesced 32B/lane) ----
  {
    int row = tid >> 4, gi = tid & 15;       // s: 1 granule/thread (512 total)
    const float* sp = s_g + (size_t)a0*NF + row*NF + gi*8;
    float4 lo = *(const float4*)sp;
    float4 hi = *(const float4*)(sp + 4);
    *(bf16x8*)&hbuf[(row*32 + (gi ^ (row & 7)))*8] = pack8(lo, hi);
    #pragma unroll
    for (int u = 0; u < 3; ++u) {            // v: 3 granules/thread (1536 total)
      int g = tid + u*512;
      int R = g >> 4, gi2 = g & 15;          // R = atom*3 + c
      int at = R / 3, c = R - 3*at;
      const float* vp = v_g + (size_t)a0*3*NF + R*NF + gi2*8;
      float4 vlo = *(const float4*)vp;
      float4 vhi = *(const float4*)(vp + 4);
      *(bf16x8*)&vcur[((c*MT + at)*16 + (gi2 ^ (at & 7)))*8] = pack8(vlo, vhi);
    }
  }
  __syncthreads();

  const float b1a  = a1b[col];
  const float b1g  = a1b[NF + col];
  const float b2s  = a2b[col];
  const float b2g  = a2b[NF + col];
  const float b2s2 = a2b[2*NF + col];

  // ================= Layer 1 =================
  // ---- Phase A: v @ [w1|w2] per c-plane; v1, n2 from same-lane accs ----
  f32x4 v1s[3][2]; float n2sq[2][4];
  {
    const __hip_bfloat16* lb = blob;
    bf16x8 w1f[4], w2f[4];
    #pragma unroll
    for (int ks = 0; ks < 4; ++ks) {
      w1f[ks] = *(const bf16x8*)&lb[OW1 + ((size_t)(wave*4 + ks)*64 + lane)*8];
      w2f[ks] = *(const bf16x8*)&lb[OW2 + ((size_t)(wave*4 + ks)*64 + lane)*8];
    }
    #pragma unroll
    for (int rt = 0; rt < 2; ++rt) { n2sq[rt][0]=0.f; n2sq[rt][1]=0.f; n2sq[rt][2]=0.f; n2sq[rt][3]=0.f; }
    #pragma unroll
    for (int c = 0; c < 3; ++c) {
      const __hip_bfloat16* vb = vcur + c*(MT*16)*8/8*1;  // plane base (bf16 idx c*MT*NF)
      const __hip_bfloat16* vp = vcur + c*MT*NF;
      (void)vb;
      #pragma unroll
      for (int rt = 0; rt < 2; ++rt) {
        int row = rt*16 + l15;
        f32x4 acc1 = {0.f,0.f,0.f,0.f}, acc2 = {0.f,0.f,0.f,0.f};
        #pragma unroll
        for (int ks = 0; ks < 4; ++ks) {
          bf16x8 af = ldfrag(vp, 16, row, ks*4 + quad);
          acc1 = __builtin_amdgcn_mfma_f32_16x16x32_bf16(af, w1f[ks], acc1, 0, 0, 0);
          acc2 = __builtin_amdgcn_mfma_f32_16x16x32_bf16(af, w2f[ks], acc2, 0, 0, 0);
        }
        v1s[c][rt] = acc1;
        #pragma unroll
        for (int i = 0; i < 4; ++i) n2sq[rt][i] += acc2[i]*acc2[i];
      }
    }
  }
  __syncthreads();   // all reads of vcur done -> safe to overwrite with v1
  {
    #pragma unroll
    for (int rt = 0; rt < 2; ++rt)
      #pragma unroll
      for (int i = 0; i < 4; ++i) {
        int row = rt*16 + quad*4 + i;
        stb(hbuf, 32, row, NF + col, sqrtf(n2sq[rt][i]));
        stb(vcur,           16, row, col, v1s[0][rt][i]);
        stb(vcur +   MT*NF, 16, row, col, v1s[1][rt][i]);
        stb(vcur + 2*MT*NF, 16, row, col, v1s[2][rt][i]);
      }
  }
  __syncthreads();

  // ---- Phase B: [s|n2] @ a1w + bias, silu -> h1 ----
  {
    const __hip_bfloat16* lb = blob;
    bf16x8 a1f[8];
    #pragma unroll
    for (int ks = 0; ks < 8; ++ks)
      a1f[ks] = *(const bf16x8*)&lb[OA1 + ((size_t)(wave*8 + ks)*64 + lane)*8];
    #pragma unroll
    for (int rt = 0; rt < 2; ++rt) {
      int row = rt*16 + l15;
      f32x4 acc = {0.f,0.f,0.f,0.f};
      #pragma unroll
      for (int ks = 0; ks < 8; ++ks) {
        bf16x8 af = ldfrag(hbuf, 32, row, ks*4 + quad);
        acc = __builtin_amdgcn_mfma_f32_16x16x32_bf16(af, a1f[ks], acc, 0, 0, 0);
      }
      #pragma unroll
      for (int i = 0; i < 4; ++i) {
        float x = acc[i] + b1a;
        stb(h1, 16, rt*16 + quad*4 + i, col, x / (1.0f + __expf(-x)));
      }
    }
  }
  __syncthreads();

  // ---- Phase C: h1 @ a2w -> s1 (hbuf) + gate * v1 (vcur, same-lane cells) ----
  {
    const __hip_bfloat16* lb = blob;
    bf16x8 asf[4], agf[4];
    #pragma unroll
    for (int ks = 0; ks < 4; ++ks) {
      asf[ks] = *(const bf16x8*)&lb[OA2 + ((size_t)(wave*4 + ks)*64 + lane)*8];
      agf[ks] = *(const bf16x8*)&lb[OA2 + ((size_t)((wave+8)*4 + ks)*64 + lane)*8];
    }
    #pragma unroll
    for (int rt = 0; rt < 2; ++rt) {
      int row = rt*16 + l15;
      f32x4 hs = {0.f,0.f,0.f,0.f}, hg = {0.f,0.f,0.f,0.f};
      #pragma unroll
      for (int ks = 0; ks < 4; ++ks) {
        bf16x8 af = ldfrag(h1, 16, row, ks*4 + quad);
        hs = __builtin_amdgcn_mfma_f32_16x16x32_bf16(af, asf[ks], hs, 0, 0, 0);
        hg = __builtin_amdgcn_mfma_f32_16x16x32_bf16(af, agf[ks], hg, 0, 0, 0);
      }
      #pragma unroll
      for (int i = 0; i < 4; ++i) {
        int r = rt*16 + quad*4 + i;
        stb(hbuf, 32, r, col, hs[i] + b2s);
        float g = hg[i] + b2g;
        stb(vcur,           16, r, col, g * ldb(vcur,           16, r, col));
        stb(vcur +   MT*NF, 16, r, col, g * ldb(vcur +   MT*NF, 16, r, col));
        stb(vcur + 2*MT*NF, 16, r, col, g * ldb(vcur + 2*MT*NF, 16, r, col));
      }
    }
  }
  __syncthreads();

  // ================= Layer 2 (v1/gate of last layer unused) =================
  // ---- Phase A': v' @ w2 -> n2 ----
  {
    const __hip_bfloat16* lb = blob + LAYER_SZ;
    bf16x8 w2f[4];
    #pragma unroll
    for (int ks = 0; ks < 4; ++ks)
      w2f[ks] = *(const bf16x8*)&lb[OW2 + ((size_t)(wave*4 + ks)*64 + lane)*8];
    #pragma unroll
    for (int rt = 0; rt < 2; ++rt) {
      int row = rt*16 + l15;
      float nq[4] = {0.f,0.f,0.f,0.f};
      #pragma unroll
      for (int c = 0; c < 3; ++c) {
        const __hip_bfloat16* vp = vcur + c*MT*NF;
        f32x4 acc = {0.f,0.f,0.f,0.f};
        #pragma unroll
        for (int ks = 0; ks < 4; ++ks) {
          bf16x8 af = ldfrag(vp, 16, row, ks*4 + quad);
          acc = __builtin_amdgcn_mfma_f32_16x16x32_bf16(af, w2f[ks], acc, 0, 0, 0);
        }
        #pragma unroll
        for (int i = 0; i < 4; ++i) nq[i] += acc[i]*acc[i];
      }
      #pragma unroll
      for (int i = 0; i < 4; ++i)
        stb(hbuf, 32, rt*16 + quad*4 + i, NF + col, sqrtf(nq[i]));
    }
  }
  __syncthreads();

  // ---- Phase B' ----
  {
    const __hip_bfloat16* lb = blob + LAYER_SZ;
    bf16x8 a1f[8];
    #pragma unroll
    for (int ks = 0; ks < 8; ++ks)
      a1f[ks] = *(const bf16x8*)&lb[OA1 + ((size_t)(wave*8 + ks)*64 + lane)*8];
    #pragma unroll
    for (int rt = 0; rt < 2; ++rt) {
      int row = rt*16 + l15;
      f32x4 acc = {0.f,0.f,0.f,0.f};
      #pragma unroll
      for (int ks = 0; ks < 8; ++ks) {
        bf16x8 af = ldfrag(hbuf, 32, row, ks*4 + quad);
        acc = __builtin_amdgcn_mfma_f32_16x16x32_bf16(af, a1f[ks], acc, 0, 0, 0);
      }
      #pragma unroll
      for (int i = 0; i < 4; ++i) {
        float x = acc[i] + b1g;
        stb(h1, 16, rt*16 + quad*4 + i, col, x / (1.0f + __expf(-x)));
      }
    }
  }
  __syncthreads();

  // ---- Phase C': s2 only -> hbuf s-half ----
  {
    const __hip_bfloat16* lb = blob + LAYER_SZ;
    bf16x8 asf[4];
    #pragma unroll
    for (int ks = 0; ks < 4; ++ks)
      asf[ks] = *(const bf16x8*)&lb[OA2 + ((size_t)(wave*4 + ks)*64 + lane)*8];
    #pragma unroll
    for (int rt = 0; rt < 2; ++rt) {
      int row = rt*16 + l15;
      f32x4 hs = {0.f,0.f,0.f,0.f};
      #pragma unroll
      for (int ks = 0; ks < 4; ++ks) {
        bf16x8 af = ldfrag(h1, 16, row, ks*4 + quad);
        hs = __builtin_amdgcn_mfma_f32_16x16x32_bf16(af, asf[ks], hs, 0, 0, 0);
      }
      #pragma unroll
      for (int i = 0; i < 4; ++i)
        stb(hbuf, 32, rt*16 + quad*4 + i, col, hs[i] + b2s2);
    }
  }
  __syncthreads();

  // ---- head: sc[atom] = dot(s2, out_w) + out_b ----
  {
    int a   = tid >> 4;        // 32 atoms x 16 threads
    int sub = tid & 15;
    float p = 0.f;
    #pragma unroll
    for (int j = 0; j < 8; ++j) {
      int f = sub*8 + j;
      p += ldb(hbuf, 32, a, f) * out_w[f];
    }
    p += __shfl_down(p, 8, 16);
    p += __shfl_down(p, 4, 16);
    p += __shfl_down(p, 2, 16);
    p += __shfl_down(p, 1, 16);
    if (sub == 0) sc[a0 + a] = p + out_b[0];
  }
}

// Stage 1: partials over 16 aligned chunks per graph (2048 blocks, float4 loads)
#define CHUNK 6256   // 16B-aligned chunk (6256*4 bytes); last chunk = 6160
__global__ __launch_bounds__(256)
void reduce_partial(const float* __restrict__ mask, const float* __restrict__ sc,
                    float* __restrict__ partial) {
  int b  = blockIdx.x >> 4;
  int ch = blockIdx.x & 15;
  int n0 = ch * CHUNK;
  int n1 = n0 + CHUNK; if (n1 > NATOMS) n1 = NATOMS;
  const float4* m4 = (const float4*)(mask + (size_t)b * NATOMS + n0);
  const float4* s4 = (const float4*)(sc + n0);
  int nq = (n1 - n0) >> 2;
  float acc = 0.f;
  for (int i = threadIdx.x; i < nq; i += 256) {
    float4 m = m4[i], s = s4[i];
    acc += m.x*s.x + m.y*s.y + m.z*s.z + m.w*s.w;
  }
  #pragma unroll
  for (int d = 32; d > 0; d >>= 1) acc += __shfl_down(acc, d, 64);
  __shared__ float red[4];
  if ((threadIdx.x & 63) == 0) red[threadIdx.x >> 6] = acc;
  __syncthreads();
  if (threadIdx.x == 0) partial[blockIdx.x] = red[0] + red[1] + red[2] + red[3];
}

__global__ void reduce_final(const float* __restrict__ partial, float* __restrict__ out) {
  int b = threadIdx.x;
  if (b < NGRAPH) {
    float s = 0.f;
    #pragma unroll
    for (int k = 0; k < 16; ++k) s += partial[b*16 + k];
    out[b] = s;
  }
}

extern "C" void kernel_launch(void* const* d_in, const int* in_sizes, int n_in,
                              void* d_out, int out_size, void* d_ws, size_t ws_size,
                              hipStream_t stream) {
  const float* s    = (const float*)d_in[0];
  const float* v    = (const float*)d_in[1];
  // d_in[2] = r, unused
  const float* mask = (const float*)d_in[3];
  const float* w1   = (const float*)d_in[4];
  const float* w2   = (const float*)d_in[5];
  const float* a1w  = (const float*)d_in[6];
  const float* a1b  = (const float*)d_in[7];
  const float* a2w  = (const float*)d_in[8];
  const float* a2b  = (const float*)d_in[9];
  const float* outw = (const float*)d_in[10];
  const float* outb = (const float*)d_in[11];

  char* ws = (char*)d_ws;
  __hip_bfloat16* blob = (__hip_bfloat16*)ws;                      // 384 KB
  float* sc      = (float*)(ws + (size_t)2*LAYER_SZ*2);            // 400 KB
  float* partial = (float*)(ws + (size_t)2*LAYER_SZ*2 + NATOMS*4); // 8 KB

  prep_weights<<<96, 256, 0, stream>>>(w1, w2, a1w, a2w, blob);
  fused_equiv<<<NBLK, NTHR, 0, stream>>>(s, v, blob, a1b, a2b, outw, outb, sc);
  reduce_partial<<<NGRAPH*16, 256, 0, stream>>>(mask, sc, partial);
  reduce_final<<<1, 128, 0, stream>>>(partial, (float*)d_out);
}